// Round 1
// baseline (1348.953 us; speedup 1.0000x reference)
//
#include <hip/hip_runtime.h>

#define NBATCH 64
#define NCH    128
#define NTYPE  6
#define NK     127
#define N1     25
#define N2     50
#define N3     100
#define NAXIS  4
#define OUTPER 400  // N3*NAXIS

__device__ __forceinline__ float tanh_fast(float x) {
    float e = __expf(2.0f * x);                       // e^{2x}; inf/0 saturate correctly
    return 1.0f - 2.0f * __builtin_amdgcn_rcpf(e + 1.0f);
}

// coords (NB,NC,3) -> ct[(j*3+d)*NB + b]  (lane=b contiguous)
__global__ void k_transpose(const float* __restrict__ coords, float* __restrict__ ct) {
    int t = blockIdx.x * blockDim.x + threadIdx.x;
    if (t >= NBATCH * NCH * 3) return;
    int b  = t & (NBATCH - 1);
    int jd = t >> 6;
    int d  = jd % 3;
    int j  = jd / 3;
    ct[t] = coords[(b * NCH + j) * 3 + d];
}

// Kernel A: t1[b,n,a,f] = sum_k env_a[b,n,k,a] * out[b,n,k,f<4]
// wave = (n, k-slice of 8), lane = b. Weights wave-uniform -> scalar loads.
__global__ __launch_bounds__(256) void k_t1(
    const float* __restrict__ ct, const int* __restrict__ types,
    const float* __restrict__ W1, const float* __restrict__ B1,
    const float* __restrict__ W2, const float* __restrict__ B2,
    const float* __restrict__ W3, const float* __restrict__ B3,
    float* __restrict__ t1buf)
{
    const int n  = blockIdx.x >> 2;
    const int qc = blockIdx.x & 3;
    const int w  = threadIdx.x >> 6;
    const int b  = threadIdx.x & 63;
    const int k0 = qc * 32 + w * 8;

    const float cx = ct[(n*3+0)*NBATCH + b];
    const float cy = ct[(n*3+1)*NBATCH + b];
    const float cz = ct[(n*3+2)*NBATCH + b];
    const int tn = __builtin_amdgcn_readfirstlane(types[n]);

    float t1a[12];
#pragma unroll
    for (int i = 0; i < 12; ++i) t1a[i] = 0.0f;

    for (int kk = 0; kk < 8; ++kk) {
        const int k = k0 + kk;
        if (k >= NK) break;
        const int j  = __builtin_amdgcn_readfirstlane((k < n) ? k : k + 1);
        const int ch = __builtin_amdgcn_readfirstlane(tn * NTYPE + types[j]);

        const float dx = cx - ct[(j*3+0)*NBATCH + b];
        const float dy = cy - ct[(j*3+1)*NBATCH + b];
        const float dz = cz - ct[(j*3+2)*NBATCH + b];
        const float d2 = dx*dx + dy*dy + dz*dz;
        const float dd = sqrtf(d2);
        const float dinv = __builtin_amdgcn_rcpf(fmaxf(dd, 1e-12f));
        const float di2 = dinv * dinv;
        const float ax = dx * di2, ay = dy * di2, az = dz * di2;

        const float* w1 = W1 + ch * N1;
        const float* b1 = B1 + ch * N1;
        float y1[N1];
#pragma unroll
        for (int o = 0; o < N1; ++o)
            y1[o] = tanh_fast(fmaf(dinv, w1[o], b1[o]));

        const float* w2 = W2 + ch * (N2 * N1);
        const float* b2 = B2 + ch * N2;
        float y2[N2];
#pragma unroll
        for (int o = 0; o < N2; ++o) {
            float z = b2[o];
#pragma unroll
            for (int i = 0; i < N1; ++i) z = fmaf(w2[o*N1+i], y1[i], z);
            y2[o] = tanh_fast(z) + y1[(o >= N1) ? (o - N1) : o];
        }

        const float* w3 = W3 + ch * (N3 * N2);
        const float* b3 = B3 + ch * N3;
#pragma unroll
        for (int f = 0; f < NAXIS; ++f) {
            float z = b3[f];
#pragma unroll
            for (int i = 0; i < N2; ++i) z = fmaf(w3[f*N2+i], y2[i], z);
            const float o4 = tanh_fast(z) + y2[f];
            t1a[0*4+f] = fmaf(ax, o4, t1a[0*4+f]);
            t1a[1*4+f] = fmaf(ay, o4, t1a[1*4+f]);
            t1a[2*4+f] = fmaf(az, o4, t1a[2*4+f]);
        }
    }

    float* dst = t1buf + (b * NCH + n) * 12;
#pragma unroll
    for (int i = 0; i < 12; ++i) atomicAdd(dst + i, t1a[i]);
}

// Kernel B: per block (n, 32-k quarter), 8 waves, lane = b.
// Phase1: wave-pairs compute y1/y2 for 4 k's into LDS (i-major, conflict-free).
// Phase2: each wave owns a 13-g slice of layer3, accumulates res over k.
__global__ __launch_bounds__(512) void k_res(
    const float* __restrict__ ct, const int* __restrict__ types,
    const float* __restrict__ W1, const float* __restrict__ B1,
    const float* __restrict__ W2, const float* __restrict__ B2,
    const float* __restrict__ W3, const float* __restrict__ B3,
    const float* __restrict__ t1buf, float* __restrict__ out)
{
    __shared__ float y2s[N2][4 * NBATCH];    // 50*256*4 = 51200 B
    __shared__ float envs[3][4 * NBATCH];    //  3*256*4 =  3072 B

    const int n    = blockIdx.x >> 2;
    const int qc   = blockIdx.x & 3;
    const int w    = threadIdx.x >> 6;
    const int b    = threadIdx.x & 63;
    const int k_lo = qc * 32;
    const int k_hi = (k_lo + 32 < NK) ? (k_lo + 32) : NK;

    const float cx = ct[(n*3+0)*NBATCH + b];
    const float cy = ct[(n*3+1)*NBATCH + b];
    const float cz = ct[(n*3+2)*NBATCH + b];
    const int tn = __builtin_amdgcn_readfirstlane(types[n]);

    float t1r[12];
#pragma unroll
    for (int i = 0; i < 12; ++i) t1r[i] = t1buf[(b * NCH + n) * 12 + i];

    const int g0 = __builtin_amdgcn_readfirstlane(w * 13);
    float racc[13][NAXIS];
#pragma unroll
    for (int gi = 0; gi < 13; ++gi)
#pragma unroll
        for (int f = 0; f < NAXIS; ++f) racc[gi][f] = 0.0f;

    for (int kb = k_lo; kb < k_hi; kb += 4) {
        // ---- phase 1 ----
        {
            const int kk2 = w >> 1;   // which k of the chunk
            const int h   = w & 1;    // which half of y2
            const int k   = kb + kk2;
            if (k < k_hi) {
                const int j  = __builtin_amdgcn_readfirstlane((k < n) ? k : k + 1);
                const int ch = __builtin_amdgcn_readfirstlane(tn * NTYPE + types[j]);
                const float dx = cx - ct[(j*3+0)*NBATCH + b];
                const float dy = cy - ct[(j*3+1)*NBATCH + b];
                const float dz = cz - ct[(j*3+2)*NBATCH + b];
                const float d2 = dx*dx + dy*dy + dz*dz;
                const float dd = sqrtf(d2);
                const float dinv = __builtin_amdgcn_rcpf(fmaxf(dd, 1e-12f));
                const float di2 = dinv * dinv;
                if (h == 0) {
                    envs[0][kk2*NBATCH + b] = dx * di2;
                    envs[1][kk2*NBATCH + b] = dy * di2;
                    envs[2][kk2*NBATCH + b] = dz * di2;
                }
                const float* w1 = W1 + ch * N1;
                const float* b1 = B1 + ch * N1;
                float y1[N1];
#pragma unroll
                for (int o = 0; o < N1; ++o)
                    y1[o] = tanh_fast(fmaf(dinv, w1[o], b1[o]));
                const int ob = h * N1;   // 0 or 25
                const float* w2 = W2 + ch * (N2*N1) + ob * N1;
                const float* b2 = B2 + ch * N2 + ob;
#pragma unroll
                for (int oi = 0; oi < N1; ++oi) {
                    float z = b2[oi];
#pragma unroll
                    for (int i = 0; i < N1; ++i) z = fmaf(w2[oi*N1+i], y1[i], z);
                    y2s[ob + oi][kk2*NBATCH + b] = tanh_fast(z) + y1[oi];
                }
            }
        }
        __syncthreads();
        // ---- phase 2 ----
        const int kmax = ((k_hi - kb) < 4) ? (k_hi - kb) : 4;
        for (int kk2 = 0; kk2 < kmax; ++kk2) {
            const int k  = kb + kk2;
            const int j  = __builtin_amdgcn_readfirstlane((k < n) ? k : k + 1);
            const int ch = __builtin_amdgcn_readfirstlane(tn * NTYPE + types[j]);

            const float ex = envs[0][kk2*NBATCH + b];
            const float ey = envs[1][kk2*NBATCH + b];
            const float ez = envs[2][kk2*NBATCH + b];
            float t2[NAXIS];
#pragma unroll
            for (int f = 0; f < NAXIS; ++f)
                t2[f] = ex*t1r[0*4+f] + ey*t1r[1*4+f] + ez*t1r[2*4+f];

            float y2r[N2];
#pragma unroll
            for (int i = 0; i < N2; ++i) y2r[i] = y2s[i][kk2*NBATCH + b];

            const float* w3base = W3 + ch * (N3*N2);
            const float* b3base = B3 + ch * N3;
#pragma unroll
            for (int gi = 0; gi < 13; ++gi) {
                const int g = g0 + gi;
                if (g < N3) {
                    const float* w3 = w3base + g * N2;
                    float z = b3base[g];
#pragma unroll
                    for (int i = 0; i < N2; ++i) z = fmaf(w3[i], y2r[i], z);
                    // residual y2[g%50] read from LDS (dynamic reg index forbidden)
                    const float o3 = tanh_fast(z) +
                        y2s[(g >= N2) ? (g - N2) : g][kk2*NBATCH + b];
#pragma unroll
                    for (int f = 0; f < NAXIS; ++f)
                        racc[gi][f] = fmaf(o3, t2[f], racc[gi][f]);
                }
            }
        }
        __syncthreads();
    }

    float* dst = out + (b * NCH + n) * OUTPER + g0 * NAXIS;
#pragma unroll
    for (int gi = 0; gi < 13; ++gi) {
        const int g = g0 + gi;
        if (g < N3) {
#pragma unroll
            for (int f = 0; f < NAXIS; ++f)
                atomicAdd(dst + gi*NAXIS + f, racc[gi][f]);
        }
    }
}

extern "C" void kernel_launch(void* const* d_in, const int* in_sizes, int n_in,
                              void* d_out, int out_size, void* d_ws, size_t ws_size,
                              hipStream_t stream) {
    const float* coords = (const float*)d_in[0];
    const int*   types  = (const int*)d_in[1];
    const float* W1 = (const float*)d_in[2];
    const float* B1 = (const float*)d_in[3];
    const float* W2 = (const float*)d_in[4];
    const float* B2 = (const float*)d_in[5];
    const float* W3 = (const float*)d_in[6];
    const float* B3 = (const float*)d_in[7];
    float* out = (float*)d_out;

    float* t1buf = (float*)d_ws;                         // 64*128*12 floats
    float* ct    = (float*)d_ws + NBATCH * NCH * 12;     // 64*128*3 floats

    hipMemsetAsync(t1buf, 0, (size_t)NBATCH * NCH * 12 * sizeof(float), stream);
    hipMemsetAsync(out, 0, (size_t)out_size * sizeof(float), stream);

    k_transpose<<<(NBATCH*NCH*3 + 255)/256, 256, 0, stream>>>(coords, ct);
    k_t1 <<<NCH*4, 256, 0, stream>>>(ct, types, W1,B1,W2,B2,W3,B3, t1buf);
    k_res<<<NCH*4, 512, 0, stream>>>(ct, types, W1,B1,W2,B2,W3,B3, t1buf, out);
}

// Round 4
// 1334.248 us; speedup vs baseline: 1.0110x; 1.0110x over previous
//
#include <hip/hip_runtime.h>

#define NBATCH 64
#define NCH    128
#define NTYPE  6
#define NK     127
#define N1     25
#define N2     50
#define N3     100
#define NAXIS  4
#define OUTPER 400  // N3*NAXIS

__device__ __forceinline__ float tanh_fast(float x) {
    float e = __expf(2.0f * x);                       // e^{2x}; inf/0 saturate correctly
    return 1.0f - 2.0f * __builtin_amdgcn_rcpf(e + 1.0f);
}

// coords (NB,NC,3) -> ct[(j*3+d)*NB + b]  (lane=b contiguous)
__global__ void k_transpose(const float* __restrict__ coords, float* __restrict__ ct) {
    int t = blockIdx.x * blockDim.x + threadIdx.x;
    if (t >= NBATCH * NCH * 3) return;
    int b  = t & (NBATCH - 1);
    int jd = t >> 6;
    int d  = jd % 3;
    int j  = jd / 3;
    ct[t] = coords[(b * NCH + j) * 3 + d];
}

// Kernel A: t1[b,n,a,f] = sum_k env_a[b,n,k,a] * out[b,n,k,f<4]
// wave = (n, k-slice of 8), lane = b. Weights wave-uniform -> scalar loads.
// (256,4): 128-VGPR cap; peak live ~95 floats (y1[25]+y2[50]+t1a[12]) fits.
__global__ __launch_bounds__(256, 4) void k_t1(
    const float* __restrict__ ct, const int* __restrict__ types,
    const float* __restrict__ W1, const float* __restrict__ B1,
    const float* __restrict__ W2, const float* __restrict__ B2,
    const float* __restrict__ W3, const float* __restrict__ B3,
    float* __restrict__ t1buf)
{
    const int n  = blockIdx.x >> 2;
    const int qc = blockIdx.x & 3;
    const int w  = threadIdx.x >> 6;
    const int b  = threadIdx.x & 63;
    const int k0 = qc * 32 + w * 8;

    const float cx = ct[(n*3+0)*NBATCH + b];
    const float cy = ct[(n*3+1)*NBATCH + b];
    const float cz = ct[(n*3+2)*NBATCH + b];
    const int tn = __builtin_amdgcn_readfirstlane(types[n]);

    float t1a[12];
#pragma unroll
    for (int i = 0; i < 12; ++i) t1a[i] = 0.0f;

    for (int kk = 0; kk < 8; ++kk) {
        const int k = k0 + kk;
        if (k >= NK) break;
        const int j  = __builtin_amdgcn_readfirstlane((k < n) ? k : k + 1);
        const int ch = __builtin_amdgcn_readfirstlane(tn * NTYPE + types[j]);

        const float dx = cx - ct[(j*3+0)*NBATCH + b];
        const float dy = cy - ct[(j*3+1)*NBATCH + b];
        const float dz = cz - ct[(j*3+2)*NBATCH + b];
        const float d2 = dx*dx + dy*dy + dz*dz;
        const float dd = sqrtf(d2);
        const float dinv = __builtin_amdgcn_rcpf(fmaxf(dd, 1e-12f));
        const float di2 = dinv * dinv;
        const float ax = dx * di2, ay = dy * di2, az = dz * di2;

        const float* w1 = W1 + ch * N1;
        const float* b1 = B1 + ch * N1;
        float y1[N1];
#pragma unroll
        for (int o = 0; o < N1; ++o)
            y1[o] = tanh_fast(fmaf(dinv, w1[o], b1[o]));

        // layer 2, i-major: zacc[50] accumulators, y1 stays live for residual
        const float* w2 = W2 + ch * (N2 * N1);
        const float* b2 = B2 + ch * N2;
        float y2[N2];
#pragma unroll
        for (int o = 0; o < N2; ++o) y2[o] = b2[o];
#pragma unroll 5
        for (int i = 0; i < N1; ++i) {
            const float yv = y1[i];
#pragma unroll
            for (int o = 0; o < N2; ++o) y2[o] = fmaf(w2[o*N1+i], yv, y2[o]);
        }
#pragma unroll
        for (int o = 0; o < N2; ++o)
            y2[o] = tanh_fast(y2[o]) + y1[(o >= N1) ? (o - N1) : o];

        const float* w3 = W3 + ch * (N3 * N2);
        const float* b3 = B3 + ch * N3;
#pragma unroll
        for (int f = 0; f < NAXIS; ++f) {
            float z = b3[f];
#pragma unroll
            for (int i = 0; i < N2; ++i) z = fmaf(w3[f*N2+i], y2[i], z);
            const float o4 = tanh_fast(z) + y2[f];
            t1a[0*4+f] = fmaf(ax, o4, t1a[0*4+f]);
            t1a[1*4+f] = fmaf(ay, o4, t1a[1*4+f]);
            t1a[2*4+f] = fmaf(az, o4, t1a[2*4+f]);
        }
    }

    float* dst = t1buf + (b * NCH + n) * 12;
#pragma unroll
    for (int i = 0; i < 12; ++i) atomicAdd(dst + i, t1a[i]);
}

// Kernel B: per block (n, 32-k quarter), 8 waves, lane = b.
// Phase1: wave-pairs compute y1/y2 for 4 k's into LDS (i-major, conflict-free).
// Phase2: i-major loop interchange — one ds_read of y2s[i] feeds 13 zacc
// accumulators; live set ~99 floats (racc 52 + zacc 13 + t1r 12 + misc)
// fits the 128-VGPR cap from (512,4) with NO scratch spills (round-1 killer).
// LDS 54 KB -> 2 blocks/CU, 16 waves/CU.
__global__ __launch_bounds__(512, 4) void k_res(
    const float* __restrict__ ct, const int* __restrict__ types,
    const float* __restrict__ W1, const float* __restrict__ B1,
    const float* __restrict__ W2, const float* __restrict__ B2,
    const float* __restrict__ W3, const float* __restrict__ B3,
    const float* __restrict__ t1buf, float* __restrict__ out)
{
    __shared__ float y2s[N2][4 * NBATCH];    // 50*256*4 = 51200 B
    __shared__ float envs[3][4 * NBATCH];    //  3*256*4 =  3072 B

    const int n    = blockIdx.x >> 2;
    const int qc   = blockIdx.x & 3;
    const int w    = threadIdx.x >> 6;
    const int b    = threadIdx.x & 63;
    const int k_lo = qc * 32;
    const int k_hi = (k_lo + 32 < NK) ? (k_lo + 32) : NK;

    const float cx = ct[(n*3+0)*NBATCH + b];
    const float cy = ct[(n*3+1)*NBATCH + b];
    const float cz = ct[(n*3+2)*NBATCH + b];
    const int tn = __builtin_amdgcn_readfirstlane(types[n]);

    float t1r[12];
#pragma unroll
    for (int i = 0; i < 12; ++i) t1r[i] = t1buf[(b * NCH + n) * 12 + i];

    const int g0 = __builtin_amdgcn_readfirstlane(w * 13);
    float racc[13][NAXIS];
#pragma unroll
    for (int gi = 0; gi < 13; ++gi)
#pragma unroll
        for (int f = 0; f < NAXIS; ++f) racc[gi][f] = 0.0f;

    for (int kb = k_lo; kb < k_hi; kb += 4) {
        // ---- phase 1: 4 k's staged by wave-pairs ----
        {
            const int kk2 = w >> 1;   // which k of the chunk
            const int h   = w & 1;    // which half of y2
            const int k   = kb + kk2;
            if (k < k_hi) {
                const int j  = __builtin_amdgcn_readfirstlane((k < n) ? k : k + 1);
                const int ch = __builtin_amdgcn_readfirstlane(tn * NTYPE + types[j]);
                const float dx = cx - ct[(j*3+0)*NBATCH + b];
                const float dy = cy - ct[(j*3+1)*NBATCH + b];
                const float dz = cz - ct[(j*3+2)*NBATCH + b];
                const float d2 = dx*dx + dy*dy + dz*dz;
                const float dd = sqrtf(d2);
                const float dinv = __builtin_amdgcn_rcpf(fmaxf(dd, 1e-12f));
                const float di2 = dinv * dinv;
                if (h == 0) {
                    envs[0][kk2*NBATCH + b] = dx * di2;
                    envs[1][kk2*NBATCH + b] = dy * di2;
                    envs[2][kk2*NBATCH + b] = dz * di2;
                }
                const float* w1 = W1 + ch * N1;
                const float* b1 = B1 + ch * N1;
                float y1[N1];
#pragma unroll
                for (int o = 0; o < N1; ++o)
                    y1[o] = tanh_fast(fmaf(dinv, w1[o], b1[o]));
                const int ob = h * N1;   // 0 or 25
                const float* w2 = W2 + ch * (N2*N1) + ob * N1;
                const float* b2 = B2 + ch * N2 + ob;
#pragma unroll 5
                for (int oi = 0; oi < N1; ++oi) {
                    float z = b2[oi];
#pragma unroll
                    for (int i = 0; i < N1; ++i) z = fmaf(w2[oi*N1+i], y1[i], z);
                    y2s[ob + oi][kk2*NBATCH + b] = tanh_fast(z) + y1[oi];
                }
            }
        }
        __syncthreads();
        // ---- phase 2: i-major layer3 + res accumulate ----
        const int kmax = ((k_hi - kb) < 4) ? (k_hi - kb) : 4;
        for (int kk2 = 0; kk2 < kmax; ++kk2) {
            const int k  = kb + kk2;
            const int j  = __builtin_amdgcn_readfirstlane((k < n) ? k : k + 1);
            const int ch = __builtin_amdgcn_readfirstlane(tn * NTYPE + types[j]);

            const float ex = envs[0][kk2*NBATCH + b];
            const float ey = envs[1][kk2*NBATCH + b];
            const float ez = envs[2][kk2*NBATCH + b];
            float t2[NAXIS];
#pragma unroll
            for (int f = 0; f < NAXIS; ++f)
                t2[f] = ex*t1r[0*4+f] + ey*t1r[1*4+f] + ez*t1r[2*4+f];

            const float* w3base = W3 + ch * (N3*N2);
            const float* b3base = B3 + ch * N3;

            float zacc[13];
#pragma unroll
            for (int gi = 0; gi < 13; ++gi)
                zacc[gi] = b3base[(g0 + gi < N3) ? (g0 + gi) : (N3 - 1)];

#pragma unroll 10
            for (int i = 0; i < N2; ++i) {
                const float yv = y2s[i][kk2*NBATCH + b];
#pragma unroll
                for (int gi = 0; gi < 13; ++gi) {
                    const int g = g0 + gi;
                    const int gg = (g < N3) ? g : (N3 - 1);
                    zacc[gi] = fmaf(w3base[gg*N2 + i], yv, zacc[gi]);
                }
            }
#pragma unroll
            for (int gi = 0; gi < 13; ++gi) {
                const int g = g0 + gi;
                if (g < N3) {
                    const float o3 = tanh_fast(zacc[gi]) +
                        y2s[(g >= N2) ? (g - N2) : g][kk2*NBATCH + b];
#pragma unroll
                    for (int f = 0; f < NAXIS; ++f)
                        racc[gi][f] = fmaf(o3, t2[f], racc[gi][f]);
                }
            }
        }
        __syncthreads();
    }

    float* dst = out + (b * NCH + n) * OUTPER + g0 * NAXIS;
#pragma unroll
    for (int gi = 0; gi < 13; ++gi) {
        const int g = g0 + gi;
        if (g < N3) {
#pragma unroll
            for (int f = 0; f < NAXIS; ++f)
                atomicAdd(dst + gi*NAXIS + f, racc[gi][f]);
        }
    }
}

extern "C" void kernel_launch(void* const* d_in, const int* in_sizes, int n_in,
                              void* d_out, int out_size, void* d_ws, size_t ws_size,
                              hipStream_t stream) {
    const float* coords = (const float*)d_in[0];
    const int*   types  = (const int*)d_in[1];
    const float* W1 = (const float*)d_in[2];
    const float* B1 = (const float*)d_in[3];
    const float* W2 = (const float*)d_in[4];
    const float* B2 = (const float*)d_in[5];
    const float* W3 = (const float*)d_in[6];
    const float* B3 = (const float*)d_in[7];
    float* out = (float*)d_out;

    float* t1buf = (float*)d_ws;                         // 64*128*12 floats
    float* ct    = (float*)d_ws + NBATCH * NCH * 12;     // 64*128*3 floats

    hipMemsetAsync(t1buf, 0, (size_t)NBATCH * NCH * 12 * sizeof(float), stream);
    hipMemsetAsync(out, 0, (size_t)out_size * sizeof(float), stream);

    k_transpose<<<(NBATCH*NCH*3 + 255)/256, 256, 0, stream>>>(coords, ct);
    k_t1 <<<NCH*4, 256, 0, stream>>>(ct, types, W1,B1,W2,B2,W3,B3, t1buf);
    k_res<<<NCH*4, 512, 0, stream>>>(ct, types, W1,B1,W2,B2,W3,B3, t1buf, out);
}